// Round 3
// baseline (292.365 us; speedup 1.0000x reference)
//
#include <hip/hip_runtime.h>

#define EPS 1e-5f

// ---------------------------------------------------------------------------
// Kernel 1: qkv[b][o][h] = BN(qkv_w @ x)   (M=512 o, N=32768 n=b*64+h, K=256)
// 64x64 tile, 256 threads, 4x4 per thread, fp32.
// ---------------------------------------------------------------------------
__global__ __launch_bounds__(256) void k_qkv_gemm(const float* __restrict__ x,
                                                  const float* __restrict__ W,
                                                  const float* __restrict__ bnq,
                                                  float* __restrict__ qkv) {
  __shared__ float As[16][64];  // [k][o]
  __shared__ float Bs[16][64];  // [k][n]
  const int tid = threadIdx.x;
  const int n0 = blockIdx.x * 64;
  const int o0 = blockIdx.y * 64;
  const int tm = tid >> 4, tn = tid & 15;
  const int arow = tid >> 2, ac4 = (tid & 3) * 4;
  const int brow = tid >> 4, bn4 = (tid & 15) * 4;
  float acc[4][4] = {{0.f}};
  for (int k0 = 0; k0 < 256; k0 += 16) {
    const float4 av = *reinterpret_cast<const float4*>(&W[(size_t)(o0 + arow) * 256 + k0 + ac4]);
    const float4 bv = *reinterpret_cast<const float4*>(&x[(size_t)(k0 + brow) * 32768 + n0 + bn4]);
    __syncthreads();
    As[ac4 + 0][arow] = av.x;
    As[ac4 + 1][arow] = av.y;
    As[ac4 + 2][arow] = av.z;
    As[ac4 + 3][arow] = av.w;
    *reinterpret_cast<float4*>(&Bs[brow][bn4]) = bv;
    __syncthreads();
#pragma unroll
    for (int kk = 0; kk < 16; ++kk) {
      const float4 a4 = *reinterpret_cast<const float4*>(&As[kk][tm * 4]);
      const float4 b4 = *reinterpret_cast<const float4*>(&Bs[kk][tn * 4]);
      const float am[4] = {a4.x, a4.y, a4.z, a4.w};
      const float bm[4] = {b4.x, b4.y, b4.z, b4.w};
#pragma unroll
      for (int im = 0; im < 4; ++im)
#pragma unroll
        for (int jn = 0; jn < 4; ++jn) acc[im][jn] = fmaf(am[im], bm[jn], acc[im][jn]);
    }
  }
  const int b = blockIdx.x;
#pragma unroll
  for (int im = 0; im < 4; ++im) {
    const int o = o0 + tm * 4 + im;
    const float sc = bnq[o] / sqrtf(bnq[1536 + o] + EPS);
    const float sh = bnq[512 + o] - bnq[1024 + o] * sc;
    float4 v;
    v.x = fmaf(acc[im][0], sc, sh);
    v.y = fmaf(acc[im][1], sc, sh);
    v.z = fmaf(acc[im][2], sc, sh);
    v.w = fmaf(acc[im][3], sc, sh);
    *reinterpret_cast<float4*>(&qkv[((size_t)b * 512 + o) * 64 + tn * 4]) = v;
  }
}

// ---------------------------------------------------------------------------
// Kernel 2: per (b,g) attention. 256 threads per block, one block per (b,g).
//   q = qkv_s rows 0..15, k = 16..31, v = 32..63  (each row = 64 h values)
//   S[i][j] = scA*qk + scB*qr + scC*kr + sh      (fused BN of the 3 sim maps)
//   P = softmax_j(S)  (deferred normalization via rowsum)
//   out[g*32+c][b][i] = bn0(sv[c][i]) + bn1(sve[c][i])
// ---------------------------------------------------------------------------
__global__ __launch_bounds__(256) void k_attn(const float* __restrict__ qkv,
                                              const float* __restrict__ rel,
                                              const float* __restrict__ bns,
                                              const float* __restrict__ bno,
                                              float* __restrict__ out) {
  __shared__ float qkv_s[64 * 65];    // [cc][h], stride 65 (bank-conflict pad)
  __shared__ float rel_s[64 * 127];   // [cc][t], stride 127 (conflict-free)
  __shared__ float S_s[64 * 65];      // scores, then reused as out-tile
  __shared__ float rowsum_s[64];
  const int tid = threadIdx.x;
  const int bg = blockIdx.x;
  const int b = bg >> 3, g = bg & 7;

  // --- stage qkv block + full relative table ---
  const float* src = qkv + ((size_t)b * 512 + (size_t)g * 64) * 64;
  for (int idx = tid; idx < 4096; idx += 256)
    qkv_s[(idx >> 6) * 65 + (idx & 63)] = src[idx];
  for (int idx = tid; idx < 64 * 127; idx += 256) rel_s[idx] = rel[idx];
  __syncthreads();

  // --- step 2: scores.  j fixed per thread; i = (tid>>6) + 4r ---
  {
    const int j = tid & 63;
    float kcol[16];
#pragma unroll
    for (int c = 0; c < 16; ++c) kcol[c] = qkv_s[(16 + c) * 65 + j];
    const float scA = bns[g] / sqrtf(bns[72 + g] + EPS);
    const float scB = bns[8 + g] / sqrtf(bns[72 + 8 + g] + EPS);
    const float scC = bns[16 + g] / sqrtf(bns[72 + 16 + g] + EPS);
    const float sh = (bns[24 + g] - bns[48 + g] * scA) +
                     (bns[24 + 8 + g] - bns[48 + 8 + g] * scB) +
                     (bns[24 + 16 + g] - bns[48 + 16 + g] * scC);
#pragma unroll 4
    for (int r = 0; r < 16; ++r) {
      const int i = (tid >> 6) + 4 * r;
      const int base = i - j + 63;  // in [0,126]
      float qk = 0.f, qr = 0.f, kr = 0.f;
#pragma unroll
      for (int c = 0; c < 16; ++c) {
        const float qv = qkv_s[c * 65 + i];
        qk = fmaf(qv, kcol[c], qk);
        qr = fmaf(qv, rel_s[c * 127 + base], qr);
        kr = fmaf(kcol[c], rel_s[(16 + c) * 127 + 126 - base], kr);
      }
      S_s[i * 65 + j] = fmaf(scA, qk, fmaf(scB, qr, fmaf(scC, kr, sh)));
    }
  }
  __syncthreads();

  // --- step 3: softmax over j (4 threads per row, shuffle reduce) ---
  {
    const int i = tid >> 2, sub = tid & 3;
    float* row = S_s + i * 65 + sub * 16;
    float m = row[0];
#pragma unroll
    for (int jj = 1; jj < 16; ++jj) m = fmaxf(m, row[jj]);
    m = fmaxf(m, __shfl_xor(m, 1));
    m = fmaxf(m, __shfl_xor(m, 2));
    float sum = 0.f;
#pragma unroll
    for (int jj = 0; jj < 16; ++jj) {
      const float e = __expf(row[jj] - m);
      row[jj] = e;
      sum += e;
    }
    sum += __shfl_xor(sum, 1);
    sum += __shfl_xor(sum, 2);
    if (sub == 0) rowsum_s[i] = sum;
  }
  __syncthreads();

  // --- step 4: sv/sve + output BN.  c fixed per thread; i = (tid>>5) + 8r ---
  const int c = tid & 31;
  float vrow[64];
#pragma unroll
  for (int jj = 0; jj < 64; ++jj) vrow[jj] = qkv_s[(32 + c) * 65 + jj];
  const float* relc = rel_s + (32 + c) * 127;
  const int ch = ((g << 5) + c) * 2;
  const float sc0 = bno[ch] / sqrtf(bno[1536 + ch] + EPS);
  const float sh0 = bno[512 + ch] - bno[1024 + ch] * sc0;
  const float sc1 = bno[ch + 1] / sqrtf(bno[1536 + ch + 1] + EPS);
  const float sh1 = bno[512 + ch + 1] - bno[1024 + ch + 1] * sc1;
  float outv[8];
#pragma unroll
  for (int r = 0; r < 8; ++r) {
    const int i = (tid >> 5) + 8 * r;
    const float* prow = S_s + i * 65;
    const float* rc = relc + i + 63;
    float sv = 0.f, sve = 0.f;
#pragma unroll
    for (int jj = 0; jj < 64; ++jj) {
      const float p = prow[jj];
      sv = fmaf(p, vrow[jj], sv);
      sve = fmaf(p, rc[-jj], sve);
    }
    const float inv = 1.0f / rowsum_s[i];
    outv[r] = fmaf(sc0, sv * inv, sh0) + fmaf(sc1, sve * inv, sh1);
  }
  __syncthreads();  // everyone done reading S_s as P
#pragma unroll
  for (int r = 0; r < 8; ++r) {
    const int i = (tid >> 5) + 8 * r;
    S_s[c * 65 + i] = outv[r];  // out-tile [c][i], stride 65
  }
  __syncthreads();
  const size_t outbase = (size_t)b * 64;
  for (int idx = tid; idx < 2048; idx += 256) {
    const int cc = idx >> 6, ii = idx & 63;
    out[(size_t)((g << 5) + cc) * 32768 + outbase + ii] = S_s[cc * 65 + ii];
  }
}

extern "C" void kernel_launch(void* const* d_in, const int* in_sizes, int n_in,
                              void* d_out, int out_size, void* d_ws, size_t ws_size,
                              hipStream_t stream) {
  const float* x = (const float*)d_in[0];         // (1,256,16,32,64)
  const float* qkv_w = (const float*)d_in[1];     // (512,256)
  const float* relative = (const float*)d_in[2];  // (64,127)
  const float* bn_qkv = (const float*)d_in[3];    // (4,512)
  const float* bn_sim = (const float*)d_in[4];    // (4,24)
  const float* bn_out = (const float*)d_in[5];    // (4,512)
  float* out = (float*)d_out;                     // (256, 512, 64) as [op][b][h]
  float* qkv = (float*)d_ws;                      // 512*512*64 floats = 64 MB

  k_qkv_gemm<<<dim3(512, 8), 256, 0, stream>>>(x, qkv_w, bn_qkv, qkv);
  k_attn<<<4096, 256, 0, stream>>>(qkv, relative, bn_sim, bn_out, out);
}